// Round 1
// baseline (1821.607 us; speedup 1.0000x reference)
//
#include <hip/hip_runtime.h>
#include <cstdint>
#include <cstddef>

#define N_NODES 100000
#define N_EDGES 1000000
#define F_IN 64
#define F_OUT 128
#define F_HID 512

__device__ __forceinline__ float elu_f(float v) {
    return v > 0.0f ? v : expm1f(v);
}

// ---------------------------------------------------------------------------
// Kernel 1: edge scatter. One wave (64 lanes) per edge; lane = feature index.
// agg_in[dst] += x[src];  agg_out[src] += x[dst];  plus degree counts.
// ---------------------------------------------------------------------------
__global__ __launch_bounds__(256) void scatter_kernel(
    const float* __restrict__ x,
    const int* __restrict__ src,
    const int* __restrict__ dst,
    float* __restrict__ agg_in, float* __restrict__ agg_out,
    float* __restrict__ cnt_in, float* __restrict__ cnt_out)
{
    long long t = (long long)blockIdx.x * 256 + threadIdx.x;
    int e = (int)(t >> 6);
    int f = (int)(t & 63);
    if (e >= N_EDGES) return;
    int s = src[e];
    int d = dst[e];
    float vs = x[(size_t)s * F_IN + f];
    float vd = x[(size_t)d * F_IN + f];
    atomicAdd(&agg_in[(size_t)d * F_IN + f], vs);
    atomicAdd(&agg_out[(size_t)s * F_IN + f], vd);
    if (f == 0) {
        atomicAdd(&cnt_in[d], 1.0f);
        atomicAdd(&cnt_out[s], 1.0f);
    }
}

// ---------------------------------------------------------------------------
// Kernel 2: out = elu( (agg/max(cnt,1)) @ W + b ).  16 nodes per 256-thr block.
// W (64x128) staged in LDS. Each thread: 1 node x 8 consecutive outputs.
// ---------------------------------------------------------------------------
__global__ __launch_bounds__(256) void sage_lin_kernel(
    const float* __restrict__ agg, const float* __restrict__ cnt,
    const float* __restrict__ W, const float* __restrict__ b,
    float* __restrict__ out)
{
    __shared__ float sW[F_IN][F_OUT];   // 32 KB
    __shared__ float sA[16][68];        // padded, ~4.3 KB

    int tid = threadIdx.x;
    int node0 = blockIdx.x * 16;

    // Load W into LDS: 8192 floats = 2048 float4, 8 per thread.
    for (int i = tid; i < F_IN * F_OUT / 4; i += 256) {
        float4 v = *reinterpret_cast<const float4*>(&W[(size_t)i * 4]);
        int k = (i * 4) >> 7, f = (i * 4) & 127;
        *reinterpret_cast<float4*>(&sW[k][f]) = v;
    }
    // Load agg rows, mean-divided: 16 rows x 16 float4 = 256, 1 per thread.
    for (int i = tid; i < 16 * 16; i += 256) {
        int nl = i >> 4, c4 = i & 15;
        int n = node0 + nl;
        float c = fmaxf(cnt[n], 1.0f);
        float4 v = *reinterpret_cast<const float4*>(&agg[(size_t)n * F_IN + c4 * 4]);
        v.x /= c; v.y /= c; v.z /= c; v.w /= c;
        *reinterpret_cast<float4*>(&sA[nl][c4 * 4]) = v;
    }
    __syncthreads();

    int nl = tid >> 4;           // 0..15
    int f0 = (tid & 15) * 8;     // 0..120
    int n = node0 + nl;

    float acc[8];
    #pragma unroll
    for (int j = 0; j < 8; ++j) acc[j] = b[f0 + j];

    for (int k = 0; k < F_IN; ++k) {
        float a = sA[nl][k];
        float4 w0 = *reinterpret_cast<const float4*>(&sW[k][f0]);
        float4 w1 = *reinterpret_cast<const float4*>(&sW[k][f0 + 4]);
        acc[0] = fmaf(a, w0.x, acc[0]);
        acc[1] = fmaf(a, w0.y, acc[1]);
        acc[2] = fmaf(a, w0.z, acc[2]);
        acc[3] = fmaf(a, w0.w, acc[3]);
        acc[4] = fmaf(a, w1.x, acc[4]);
        acc[5] = fmaf(a, w1.y, acc[5]);
        acc[6] = fmaf(a, w1.z, acc[6]);
        acc[7] = fmaf(a, w1.w, acc[7]);
    }
    float4 o0 = make_float4(elu_f(acc[0]), elu_f(acc[1]), elu_f(acc[2]), elu_f(acc[3]));
    float4 o1 = make_float4(elu_f(acc[4]), elu_f(acc[5]), elu_f(acc[6]), elu_f(acc[7]));
    *reinterpret_cast<float4*>(&out[(size_t)n * F_OUT + f0]) = o0;
    *reinterpret_cast<float4*>(&out[(size_t)n * F_OUT + f0 + 4]) = o1;
}

// ---------------------------------------------------------------------------
// Kernel 3: x_self = elu( elu(x@W1+b1) @ W2 + b2 ).
// 32 nodes per 256-thread block; hidden dim (512) processed in chunks of 64.
// LDS: sX 8.7K + sH 8.7K + sW1 16K + sW2 32K = ~66 KB -> 2 blocks/CU.
// Each thread: 2 nodes x 8 outputs = 16 accumulators.
// ---------------------------------------------------------------------------
__global__ __launch_bounds__(256) void self_mlp_kernel(
    const float* __restrict__ x,
    const float* __restrict__ W1, const float* __restrict__ b1,
    const float* __restrict__ W2, const float* __restrict__ b2,
    float* __restrict__ out)
{
    __shared__ float sX[32][68];
    __shared__ float sH[32][68];
    __shared__ float sW1[64][64];
    __shared__ float sW2[64][128];
    __shared__ float sb1[64];

    int tid = threadIdx.x;
    int node0 = blockIdx.x * 32;

    // Load x rows: 32 x 16 float4 = 512, 2 per thread.
    for (int i = tid; i < 32 * 16; i += 256) {
        int nl = i >> 4, c4 = i & 15;
        float4 v = *reinterpret_cast<const float4*>(&x[(size_t)(node0 + nl) * F_IN + c4 * 4]);
        *reinterpret_cast<float4*>(&sX[nl][c4 * 4]) = v;
    }

    int nl0 = (tid >> 4) * 2;     // 0,2,..,30
    int f0 = (tid & 15) * 8;      // 0..120
    float acc0[8], acc1[8];
    #pragma unroll
    for (int j = 0; j < 8; ++j) { acc0[j] = b2[f0 + j]; acc1[j] = b2[f0 + j]; }

    for (int c = 0; c < 8; ++c) {
        int hid0 = c * 64;
        __syncthreads();   // previous chunk's reads done before overwriting LDS
        // sW1 chunk: 64x64 -> 1024 float4, 4 per thread.
        for (int i = tid; i < 64 * 16; i += 256) {
            int k = i >> 4, c4 = i & 15;
            float4 v = *reinterpret_cast<const float4*>(&W1[(size_t)k * F_HID + hid0 + c4 * 4]);
            *reinterpret_cast<float4*>(&sW1[k][c4 * 4]) = v;
        }
        // sW2 chunk: 64x128 -> 2048 float4, 8 per thread.
        for (int i = tid; i < 64 * 32; i += 256) {
            int j = i >> 5, c4 = i & 31;
            float4 v = *reinterpret_cast<const float4*>(&W2[(size_t)(hid0 + j) * F_OUT + c4 * 4]);
            *reinterpret_cast<float4*>(&sW2[j][c4 * 4]) = v;
        }
        if (tid < 64) sb1[tid] = b1[hid0 + tid];
        __syncthreads();

        // h = elu(x @ W1chunk + b1chunk): 32x64 values, 8 per thread.
        {
            int hn = tid >> 3;          // 0..31
            int j0 = (tid & 7) * 8;     // 0..56
            float h[8];
            #pragma unroll
            for (int j = 0; j < 8; ++j) h[j] = sb1[j0 + j];
            for (int k = 0; k < 64; ++k) {
                float a = sX[hn][k];
                float4 w0 = *reinterpret_cast<const float4*>(&sW1[k][j0]);
                float4 w1 = *reinterpret_cast<const float4*>(&sW1[k][j0 + 4]);
                h[0] = fmaf(a, w0.x, h[0]);
                h[1] = fmaf(a, w0.y, h[1]);
                h[2] = fmaf(a, w0.z, h[2]);
                h[3] = fmaf(a, w0.w, h[3]);
                h[4] = fmaf(a, w1.x, h[4]);
                h[5] = fmaf(a, w1.y, h[5]);
                h[6] = fmaf(a, w1.z, h[6]);
                h[7] = fmaf(a, w1.w, h[7]);
            }
            #pragma unroll
            for (int j = 0; j < 8; ++j) h[j] = elu_f(h[j]);
            *reinterpret_cast<float4*>(&sH[hn][j0]) = make_float4(h[0], h[1], h[2], h[3]);
            *reinterpret_cast<float4*>(&sH[hn][j0 + 4]) = make_float4(h[4], h[5], h[6], h[7]);
        }
        __syncthreads();

        // acc += h @ W2chunk
        for (int j2 = 0; j2 < 64; ++j2) {
            float h0 = sH[nl0][j2];
            float h1 = sH[nl0 + 1][j2];
            float4 wa = *reinterpret_cast<const float4*>(&sW2[j2][f0]);
            float4 wb = *reinterpret_cast<const float4*>(&sW2[j2][f0 + 4]);
            acc0[0] = fmaf(h0, wa.x, acc0[0]);  acc1[0] = fmaf(h1, wa.x, acc1[0]);
            acc0[1] = fmaf(h0, wa.y, acc0[1]);  acc1[1] = fmaf(h1, wa.y, acc1[1]);
            acc0[2] = fmaf(h0, wa.z, acc0[2]);  acc1[2] = fmaf(h1, wa.z, acc1[2]);
            acc0[3] = fmaf(h0, wa.w, acc0[3]);  acc1[3] = fmaf(h1, wa.w, acc1[3]);
            acc0[4] = fmaf(h0, wb.x, acc0[4]);  acc1[4] = fmaf(h1, wb.x, acc1[4]);
            acc0[5] = fmaf(h0, wb.y, acc0[5]);  acc1[5] = fmaf(h1, wb.y, acc1[5]);
            acc0[6] = fmaf(h0, wb.z, acc0[6]);  acc1[6] = fmaf(h1, wb.z, acc1[6]);
            acc0[7] = fmaf(h0, wb.w, acc0[7]);  acc1[7] = fmaf(h1, wb.w, acc1[7]);
        }
    }

    // Epilogue
    int n0 = node0 + nl0;
    float4 a0 = make_float4(elu_f(acc0[0]), elu_f(acc0[1]), elu_f(acc0[2]), elu_f(acc0[3]));
    float4 a1 = make_float4(elu_f(acc0[4]), elu_f(acc0[5]), elu_f(acc0[6]), elu_f(acc0[7]));
    float4 b0 = make_float4(elu_f(acc1[0]), elu_f(acc1[1]), elu_f(acc1[2]), elu_f(acc1[3]));
    float4 b1v = make_float4(elu_f(acc1[4]), elu_f(acc1[5]), elu_f(acc1[6]), elu_f(acc1[7]));
    *reinterpret_cast<float4*>(&out[(size_t)n0 * F_OUT + f0]) = a0;
    *reinterpret_cast<float4*>(&out[(size_t)n0 * F_OUT + f0 + 4]) = a1;
    *reinterpret_cast<float4*>(&out[(size_t)(n0 + 1) * F_OUT + f0]) = b0;
    *reinterpret_cast<float4*>(&out[(size_t)(n0 + 1) * F_OUT + f0 + 4]) = b1v;
}

// ---------------------------------------------------------------------------

extern "C" void kernel_launch(void* const* d_in, const int* in_sizes, int n_in,
                              void* d_out, int out_size, void* d_ws, size_t ws_size,
                              hipStream_t stream) {
    const float* x     = (const float*)d_in[0];
    const int*   ei    = (const int*)d_in[1];     // int32 (jax default; harness int)
    const float* W_in  = (const float*)d_in[2];
    const float* b_in  = (const float*)d_in[3];
    const float* W_out = (const float*)d_in[4];
    const float* b_out = (const float*)d_in[5];
    const float* W1    = (const float*)d_in[6];
    const float* b1    = (const float*)d_in[7];
    const float* W2    = (const float*)d_in[8];
    const float* b2    = (const float*)d_in[9];
    float* out = (float*)d_out;

    const int* src = ei;
    const int* dst = ei + N_EDGES;

    float* agg_in  = (float*)d_ws;                         // 100000*64
    float* agg_out = agg_in + (size_t)N_NODES * F_IN;      // 100000*64
    float* cnt_in  = agg_out + (size_t)N_NODES * F_IN;     // 100000
    float* cnt_out = cnt_in + N_NODES;                     // 100000

    size_t zero_floats = 2 * (size_t)N_NODES * F_IN + 2 * (size_t)N_NODES;
    hipMemsetAsync(d_ws, 0, zero_floats * sizeof(float), stream);

    // Scatter: 1M edges x 64 lanes = 64M threads.
    long long total = (long long)N_EDGES * 64;
    int blocks = (int)((total + 255) / 256);
    scatter_kernel<<<blocks, 256, 0, stream>>>(x, src, dst, agg_in, agg_out, cnt_in, cnt_out);

    // Two direction-wise SAGE linears (100000/16 = 6250 blocks each).
    sage_lin_kernel<<<6250, 256, 0, stream>>>(agg_in, cnt_in, W_in, b_in,
                                              out);
    sage_lin_kernel<<<6250, 256, 0, stream>>>(agg_out, cnt_out, W_out, b_out,
                                              out + (size_t)N_NODES * F_OUT);

    // Self MLP (100000/32 = 3125 blocks).
    self_mlp_kernel<<<3125, 256, 0, stream>>>(x, W1, b1, W2, b2,
                                              out + 2 * (size_t)N_NODES * F_OUT);
}

// Round 2
// 1225.314 us; speedup vs baseline: 1.4866x; 1.4866x over previous
//
#include <hip/hip_runtime.h>
#include <cstdint>
#include <cstddef>

#define N_NODES 100000
#define N_EDGES 1000000
#define F_IN 64
#define F_OUT 128
#define F_HID 512

__device__ __forceinline__ float elu_f(float v) {
    return v > 0.0f ? v : expm1f(v);
}

// ---------------------------------------------------------------------------
// Kernel 1: edge scatter. One wave (64 lanes) per edge; lane = feature index.
// agg_in[dst] += x[src];  agg_out[src] += x[dst];  plus degree counts.
// ---------------------------------------------------------------------------
__global__ __launch_bounds__(256) void scatter_kernel(
    const float* __restrict__ x,
    const int* __restrict__ src,
    const int* __restrict__ dst,
    float* __restrict__ agg_in, float* __restrict__ agg_out,
    float* __restrict__ cnt_in, float* __restrict__ cnt_out)
{
    long long t = (long long)blockIdx.x * 256 + threadIdx.x;
    int e = (int)(t >> 6);
    int f = (int)(t & 63);
    if (e >= N_EDGES) return;
    int s = src[e];
    int d = dst[e];
    float vs = x[(size_t)s * F_IN + f];
    float vd = x[(size_t)d * F_IN + f];
    atomicAdd(&agg_in[(size_t)d * F_IN + f], vs);
    atomicAdd(&agg_out[(size_t)s * F_IN + f], vd);
    if (f == 0) {
        atomicAdd(&cnt_in[d], 1.0f);
        atomicAdd(&cnt_out[s], 1.0f);
    }
}

// ---------------------------------------------------------------------------
// Kernel 2: out = elu( (agg/max(cnt,1)) @ W + b ).  16 nodes per 256-thr block.
// W (64x128) staged in LDS. Each thread: 1 node x 8 consecutive outputs.
// ---------------------------------------------------------------------------
__global__ __launch_bounds__(256) void sage_lin_kernel(
    const float* __restrict__ agg, const float* __restrict__ cnt,
    const float* __restrict__ W, const float* __restrict__ b,
    float* __restrict__ out)
{
    __shared__ float sW[F_IN][F_OUT];   // 32 KB
    __shared__ float sA[16][68];        // padded, ~4.3 KB

    int tid = threadIdx.x;
    int node0 = blockIdx.x * 16;

    // Load W into LDS: 8192 floats = 2048 float4, 8 per thread.
    for (int i = tid; i < F_IN * F_OUT / 4; i += 256) {
        float4 v = *reinterpret_cast<const float4*>(&W[(size_t)i * 4]);
        int k = (i * 4) >> 7, f = (i * 4) & 127;
        *reinterpret_cast<float4*>(&sW[k][f]) = v;
    }
    // Load agg rows, mean-divided: 16 rows x 16 float4 = 256, 1 per thread.
    for (int i = tid; i < 16 * 16; i += 256) {
        int nl = i >> 4, c4 = i & 15;
        int n = node0 + nl;
        float c = fmaxf(cnt[n], 1.0f);
        float4 v = *reinterpret_cast<const float4*>(&agg[(size_t)n * F_IN + c4 * 4]);
        v.x /= c; v.y /= c; v.z /= c; v.w /= c;
        *reinterpret_cast<float4*>(&sA[nl][c4 * 4]) = v;
    }
    __syncthreads();

    int nl = tid >> 4;           // 0..15
    int f0 = (tid & 15) * 8;     // 0..120
    int n = node0 + nl;

    float acc[8];
    #pragma unroll
    for (int j = 0; j < 8; ++j) acc[j] = b[f0 + j];

    for (int k = 0; k < F_IN; ++k) {
        float a = sA[nl][k];
        float4 w0 = *reinterpret_cast<const float4*>(&sW[k][f0]);
        float4 w1 = *reinterpret_cast<const float4*>(&sW[k][f0 + 4]);
        acc[0] = fmaf(a, w0.x, acc[0]);
        acc[1] = fmaf(a, w0.y, acc[1]);
        acc[2] = fmaf(a, w0.z, acc[2]);
        acc[3] = fmaf(a, w0.w, acc[3]);
        acc[4] = fmaf(a, w1.x, acc[4]);
        acc[5] = fmaf(a, w1.y, acc[5]);
        acc[6] = fmaf(a, w1.z, acc[6]);
        acc[7] = fmaf(a, w1.w, acc[7]);
    }
    float4 o0 = make_float4(elu_f(acc[0]), elu_f(acc[1]), elu_f(acc[2]), elu_f(acc[3]));
    float4 o1 = make_float4(elu_f(acc[4]), elu_f(acc[5]), elu_f(acc[6]), elu_f(acc[7]));
    *reinterpret_cast<float4*>(&out[(size_t)n * F_OUT + f0]) = o0;
    *reinterpret_cast<float4*>(&out[(size_t)n * F_OUT + f0 + 4]) = o1;
}

// ---------------------------------------------------------------------------
// Kernel 3 v2: x_self = elu( elu(x@W1+b1) @ W2 + b2 ).
// 128 nodes per 256-thread block; hidden chunked by 16 (32 chunks).
// Transposed LDS layouts so all hot-loop reads are ds_read_b128:
//   sXT[k][node], sHT[hid][node], sW2[hid][f].
// LDS = 32K + 4K + 8K + 8K = 52 KB -> 3 blocks/CU. Stage2: 8x8 register tile.
// ---------------------------------------------------------------------------
__global__ __launch_bounds__(256, 3) void self_mlp_kernel(
    const float* __restrict__ x,
    const float* __restrict__ W1, const float* __restrict__ b1,
    const float* __restrict__ W2, const float* __restrict__ b2,
    float* __restrict__ out)
{
    __shared__ float sXT[F_IN][128];    // [k][node]   32 KB
    __shared__ float sW1[F_IN][16];     // [k][hid]     4 KB
    __shared__ float sHT[16][128];      // [hid][node]  8 KB
    __shared__ float sW2[16][128];      // [hid][f]     8 KB
    __shared__ float sb1[16];

    int tid = threadIdx.x;
    int node0 = blockIdx.x * 128;

    // Load x transposed into sXT: 2048 float4 reads, scalar transpose writes.
    // Lanes are consecutive in node -> LDS writes conflict-free (bank = node%32).
    #pragma unroll
    for (int it = 0; it < 8; ++it) {
        int fid = tid + it * 256;            // 0..2047
        int node = fid & 127, k4 = fid >> 7; // k4 0..15
        int n = node0 + node;
        if (n > N_NODES - 1) n = N_NODES - 1;
        float4 v = *reinterpret_cast<const float4*>(&x[(size_t)n * F_IN + k4 * 4]);
        sXT[k4 * 4 + 0][node] = v.x;
        sXT[k4 * 4 + 1][node] = v.y;
        sXT[k4 * 4 + 2][node] = v.z;
        sXT[k4 * 4 + 3][node] = v.w;
    }

    // Stage-2 mapping: 8 nodes x 8 outs per thread.
    int og = tid & 15;          // f0 = og*8
    int ng = tid >> 4;          // nodes ng*8 .. +7
    int f0 = og * 8;
    // Stage-1 mapping: 4 nodes x 2 hids per thread.
    int ng1 = tid & 31;         // nodes ng1*4 .. +3
    int hg = tid >> 5;          // hids hg*2 .. +1

    float acc[8][8];
    {
        float4 bv0 = *reinterpret_cast<const float4*>(&b2[f0]);
        float4 bv1 = *reinterpret_cast<const float4*>(&b2[f0 + 4]);
        #pragma unroll
        for (int i = 0; i < 8; ++i) {
            acc[i][0] = bv0.x; acc[i][1] = bv0.y; acc[i][2] = bv0.z; acc[i][3] = bv0.w;
            acc[i][4] = bv1.x; acc[i][5] = bv1.y; acc[i][6] = bv1.z; acc[i][7] = bv1.w;
        }
    }

    for (int c = 0; c < 32; ++c) {
        int hid0 = c * 16;
        __syncthreads();   // previous chunk's reads done before overwrite

        // sW1 chunk: 64x16 = 256 float4, 1 per thread.
        {
            int k = tid >> 2, h4 = tid & 3;
            float4 v = *reinterpret_cast<const float4*>(&W1[(size_t)k * F_HID + hid0 + h4 * 4]);
            *reinterpret_cast<float4*>(&sW1[k][h4 * 4]) = v;
        }
        // sW2 chunk: 16x128 = 512 float4, 2 per thread.
        #pragma unroll
        for (int it = 0; it < 2; ++it) {
            int fid = tid + it * 256;
            int j = fid >> 5, f4 = fid & 31;
            float4 v = *reinterpret_cast<const float4*>(&W2[(size_t)(hid0 + j) * F_OUT + f4 * 4]);
            *reinterpret_cast<float4*>(&sW2[j][f4 * 4]) = v;
        }
        if (tid < 16) sb1[tid] = b1[hid0 + tid];
        __syncthreads();

        // Stage 1: h = elu(x @ W1chunk + b1chunk), written transposed to sHT.
        {
            float h0[4], h1[4];
            float bb0 = sb1[hg * 2], bb1 = sb1[hg * 2 + 1];
            #pragma unroll
            for (int i = 0; i < 4; ++i) { h0[i] = bb0; h1[i] = bb1; }
            #pragma unroll 8
            for (int k = 0; k < F_IN; ++k) {
                float4 a = *reinterpret_cast<const float4*>(&sXT[k][ng1 * 4]);
                float w0 = sW1[k][hg * 2];
                float w1 = sW1[k][hg * 2 + 1];
                h0[0] = fmaf(w0, a.x, h0[0]);
                h0[1] = fmaf(w0, a.y, h0[1]);
                h0[2] = fmaf(w0, a.z, h0[2]);
                h0[3] = fmaf(w0, a.w, h0[3]);
                h1[0] = fmaf(w1, a.x, h1[0]);
                h1[1] = fmaf(w1, a.y, h1[1]);
                h1[2] = fmaf(w1, a.z, h1[2]);
                h1[3] = fmaf(w1, a.w, h1[3]);
            }
            float4 o0 = make_float4(elu_f(h0[0]), elu_f(h0[1]), elu_f(h0[2]), elu_f(h0[3]));
            float4 o1 = make_float4(elu_f(h1[0]), elu_f(h1[1]), elu_f(h1[2]), elu_f(h1[3]));
            *reinterpret_cast<float4*>(&sHT[hg * 2][ng1 * 4]) = o0;
            *reinterpret_cast<float4*>(&sHT[hg * 2 + 1][ng1 * 4]) = o1;
        }
        __syncthreads();

        // Stage 2: acc += hT @ W2chunk  (8x8 outer product per thread per k).
        #pragma unroll 4
        for (int k = 0; k < 16; ++k) {
            float4 ha = *reinterpret_cast<const float4*>(&sHT[k][ng * 8]);
            float4 hb = *reinterpret_cast<const float4*>(&sHT[k][ng * 8 + 4]);
            float4 wa = *reinterpret_cast<const float4*>(&sW2[k][f0]);
            float4 wb = *reinterpret_cast<const float4*>(&sW2[k][f0 + 4]);
            float hv[8] = {ha.x, ha.y, ha.z, ha.w, hb.x, hb.y, hb.z, hb.w};
            float wv[8] = {wa.x, wa.y, wa.z, wa.w, wb.x, wb.y, wb.z, wb.w};
            #pragma unroll
            for (int i = 0; i < 8; ++i) {
                #pragma unroll
                for (int j = 0; j < 8; ++j) {
                    acc[i][j] = fmaf(hv[i], wv[j], acc[i][j]);
                }
            }
        }
    }

    // Epilogue: elu + store.
    #pragma unroll
    for (int i = 0; i < 8; ++i) {
        int n = node0 + ng * 8 + i;
        if (n < N_NODES) {
            float4 o0 = make_float4(elu_f(acc[i][0]), elu_f(acc[i][1]),
                                    elu_f(acc[i][2]), elu_f(acc[i][3]));
            float4 o1 = make_float4(elu_f(acc[i][4]), elu_f(acc[i][5]),
                                    elu_f(acc[i][6]), elu_f(acc[i][7]));
            *reinterpret_cast<float4*>(&out[(size_t)n * F_OUT + f0]) = o0;
            *reinterpret_cast<float4*>(&out[(size_t)n * F_OUT + f0 + 4]) = o1;
        }
    }
}

// ---------------------------------------------------------------------------

extern "C" void kernel_launch(void* const* d_in, const int* in_sizes, int n_in,
                              void* d_out, int out_size, void* d_ws, size_t ws_size,
                              hipStream_t stream) {
    const float* x     = (const float*)d_in[0];
    const int*   ei    = (const int*)d_in[1];     // int32 (jax default; harness int)
    const float* W_in  = (const float*)d_in[2];
    const float* b_in  = (const float*)d_in[3];
    const float* W_out = (const float*)d_in[4];
    const float* b_out = (const float*)d_in[5];
    const float* W1    = (const float*)d_in[6];
    const float* b1    = (const float*)d_in[7];
    const float* W2    = (const float*)d_in[8];
    const float* b2    = (const float*)d_in[9];
    float* out = (float*)d_out;

    const int* src = ei;
    const int* dst = ei + N_EDGES;

    float* agg_in  = (float*)d_ws;                         // 100000*64
    float* agg_out = agg_in + (size_t)N_NODES * F_IN;      // 100000*64
    float* cnt_in  = agg_out + (size_t)N_NODES * F_IN;     // 100000
    float* cnt_out = cnt_in + N_NODES;                     // 100000

    size_t zero_floats = 2 * (size_t)N_NODES * F_IN + 2 * (size_t)N_NODES;
    hipMemsetAsync(d_ws, 0, zero_floats * sizeof(float), stream);

    // Scatter: 1M edges x 64 lanes = 64M threads.
    long long total = (long long)N_EDGES * 64;
    int blocks = (int)((total + 255) / 256);
    scatter_kernel<<<blocks, 256, 0, stream>>>(x, src, dst, agg_in, agg_out, cnt_in, cnt_out);

    // Two direction-wise SAGE linears (100000/16 = 6250 blocks each).
    sage_lin_kernel<<<6250, 256, 0, stream>>>(agg_in, cnt_in, W_in, b_in,
                                              out);
    sage_lin_kernel<<<6250, 256, 0, stream>>>(agg_out, cnt_out, W_out, b_out,
                                              out + (size_t)N_NODES * F_OUT);

    // Self MLP (ceil(100000/128) = 782 blocks).
    self_mlp_kernel<<<782, 256, 0, stream>>>(x, W1, b1, W2, b2,
                                             out + 2 * (size_t)N_NODES * F_OUT);
}